// Round 25
// baseline (589.311 us; speedup 1.0000x reference)
//
#include <hip/hip_runtime.h>
#include <math.h>

#define BATCH 65536
#define KIN   784
#define HD    768
#define FCAP  16384

typedef float f32x4 __attribute__((ext_vector_type(4)));
typedef short s16x8 __attribute__((ext_vector_type(8)));
typedef unsigned int __attribute__((address_space(3))) lds_u32;
typedef const unsigned int __attribute__((address_space(1))) glb_u32;

__device__ __forceinline__ float frelu(float x){ return x > 0.f ? x : 0.f; }

__device__ __forceinline__ unsigned int cvtpk(float a, float b){
    unsigned int r;
    asm("v_cvt_pk_bf16_f32 %0, %1, %2" : "=v"(r) : "v"(a), "v"(b));
    return r;
}
__device__ __forceinline__ unsigned short f2bf(float v){
    unsigned int u = __builtin_bit_cast(unsigned int, v);
    u += 0x7FFFu + ((u >> 16) & 1u);
    return (unsigned short)(u >> 16);
}
__device__ __forceinline__ float bf2f(unsigned short s){
    unsigned int u = ((unsigned int)s) << 16;
    return __builtin_bit_cast(float, u);
}
__device__ __forceinline__ void gload16(const void* g, void* l){
    __builtin_amdgcn_global_load_lds((glb_u32*)g, (lds_u32*)l, 16, 0, 0);
}

// ---------------------------------------------------------------------------
// x [B,784] fp32 -> xbf [B,832] bf16 (pad zeroed; 832 = 13*64 for BK=64).
// ---------------------------------------------------------------------------
__global__ __launch_bounds__(256)
void cvtX(const float* __restrict__ x, unsigned short* __restrict__ xbf)
{
    int idx = blockIdx.x * 256 + threadIdx.x;     // BATCH*104 total
    int row = idx / 104, c = (idx - row * 104) * 8;
    uint4 o = make_uint4(0, 0, 0, 0);
    if (c < KIN) {
        const float* p = x + (size_t)row * KIN + c;
        float4 a = *(const float4*)p;
        float4 b = *(const float4*)(p + 4);
        o.x = cvtpk(a.x, a.y); o.y = cvtpk(a.z, a.w);
        o.z = cvtpk(b.x, b.y); o.w = cvtpk(b.z, b.w);
    }
    *(uint4*)(xbf + (size_t)row * 832 + c) = o;
}

// ---------------------------------------------------------------------------
// feat = relu(hbf*scale + shift) -> fbf (bf16). 8 elems/thread.
// ---------------------------------------------------------------------------
__global__ __launch_bounds__(256)
void featBN(const unsigned short* __restrict__ hbf,
            const float* __restrict__ scale, const float* __restrict__ shift,
            unsigned short* __restrict__ fbf)
{
    int idx = blockIdx.x * 256 + threadIdx.x;     // BATCH*96 total
    int row = idx / 96, c = (idx - row * 96) * 8;
    s16x8 hv = *(const s16x8*)(hbf + (size_t)row * HD + c);
    float4 s0 = *(const float4*)(scale + c), s1 = *(const float4*)(scale + c + 4);
    float4 t0 = *(const float4*)(shift + c), t1 = *(const float4*)(shift + c + 4);
    float v[8];
    v[0] = frelu(bf2f((unsigned short)hv[0]) * s0.x + t0.x);
    v[1] = frelu(bf2f((unsigned short)hv[1]) * s0.y + t0.y);
    v[2] = frelu(bf2f((unsigned short)hv[2]) * s0.z + t0.z);
    v[3] = frelu(bf2f((unsigned short)hv[3]) * s0.w + t0.w);
    v[4] = frelu(bf2f((unsigned short)hv[4]) * s1.x + t1.x);
    v[5] = frelu(bf2f((unsigned short)hv[5]) * s1.y + t1.y);
    v[6] = frelu(bf2f((unsigned short)hv[6]) * s1.z + t1.z);
    v[7] = frelu(bf2f((unsigned short)hv[7]) * s1.w + t1.w);
    uint4 o;
    o.x = cvtpk(v[0], v[1]); o.y = cvtpk(v[2], v[3]);
    o.z = cvtpk(v[4], v[5]); o.w = cvtpk(v[6], v[7]);
    *(uint4*)(fbf + (size_t)row * HD + c) = o;
}

// ---------------------------------------------------------------------------
// Pre-tile W[K][N] fp32 -> bf16 hi AND lo 8KB swizzled chunks (128-col tiles).
// ---------------------------------------------------------------------------
__global__ __launch_bounds__(256)
void tileW(const float* __restrict__ W, char* __restrict__ Wh, char* __restrict__ Wl,
           int K, int N, int NT)
{
    int chunk = blockIdx.x;
    int nb = chunk / NT, t = chunk - nb * NT;
    int tid = threadIdx.x;
    #pragma unroll
    for (int q = 0; q < 2; q++) {
        int idx = q * 256 + tid;
        int r = idx >> 2, p = idx & 3;
        int s = (p ^ ((r >> 1) & 3)) & 3;
        int kb = t * 32 + s * 8;
        int n = nb * 128 + r;
        s16x8 hv, lv;
        #pragma unroll
        for (int e = 0; e < 8; e++) {
            int k = kb + e;
            float v = (k < K) ? W[(size_t)k * N + n] : 0.f;
            unsigned short h = f2bf(v);
            hv[e] = (short)h;
            lv[e] = (short)f2bf(v - bf2f(h));
        }
        *(s16x8*)(Wh + (size_t)chunk * 8192 + idx * 16) = hv;
        *(s16x8*)(Wl + (size_t)chunk * 8192 + idx * 16) = lv;
    }
}

// ---- Wa[d] 768x64 -> 24 chunks of 4KB per domain (64-row swizzled image) ---
__global__ __launch_bounds__(256)
void tileWa(const float* __restrict__ Wa, char* __restrict__ WaC)
{
    int chunk = blockIdx.x;            // d*24 + t
    int d = chunk / 24, t = chunk - d * 24;
    int idx = threadIdx.x;
    int r = idx >> 2, p = idx & 3;     // r = expert col (0..63)
    int s = (p ^ ((r >> 1) & 3)) & 3;
    int kb = t * 32 + s * 8;
    s16x8 hv;
    #pragma unroll
    for (int e = 0; e < 8; e++)
        hv[e] = (short)f2bf(Wa[((size_t)d * HD + kb + e) * 64 + r]);
    *(s16x8*)(WaC + (size_t)chunk * 4096 + idx * 16) = hv;
}

// ---------------------------------------------------------------------------
// DUAL-N bf16 GEMM: 512 threads (8 waves, 2M x 4N), tile 128 x 256, BK=64.
// A staged once per iter and shared by BOTH 128-col subtiles (A-bytes per
// unit work halve; barrier-pairs per unit work halve). Per-wave acc stays
// 4x4 (64 VGPR) — avoids r21's VGPR blowup by adding waves, not per-thread
// work. LDS 48KB (A 2x8K | B 4x8K) -> 3 blocks/CU = 24 waves/CU.
// B reuses the 128-col pre-tiled chunk images: col-tile ct uses nb=2ct,2ct+1.
// Per-subtile k-order identical to r23/r24 -> h and partials bitwise same.
// MODE 0: A=xbf(KP=832); epilogue h(bf16) + fused BN column partials.
// MODE 1: A=fbf(KP=768); epilogue a=relu(acc+bd1); domacc += a @ Wd2.
// ---------------------------------------------------------------------------
template<int MODE>
__global__ __launch_bounds__(512)
void gemm97(const unsigned short* __restrict__ Abf,
            const char* __restrict__ BhC,
            const float* __restrict__ bias,
            unsigned short* __restrict__ Hbf,
            const float* __restrict__ Wd2, double* __restrict__ domacc,
            float* __restrict__ sp1, float* __restrict__ sp2,
            int KP, int NT)
{
    __shared__ __align__(16) char sm[49152];   // A0|A1 (16K) then B[h][cc] (32K)

    int bid = blockIdx.x;
    int wg = (bid & 7) * 192 + (bid >> 3);     // XCD-contiguous remap (1536)
    int mb = wg / 3, ct = wg - mb * 3;         // 512 M-panels x 3 col-tiles
    int m0 = mb << 7, n0 = ct << 8;            // 128 rows, 256 cols

    int tid = threadIdx.x;
    int lane = tid & 63, wid = tid >> 6;       // 8 waves
    int wr = wid >> 2, wc = wid & 3;           // 2M x 4N wave grid
    int l15 = lane & 15, l4 = lane >> 4;

    int aoff[4], boff[4];
    #pragma unroll
    for (int f = 0; f < 4; f++) {
        int ra = wr * 64 + f * 16 + l15;
        aoff[f] = ra * 64 + (((l4 ^ (ra >> 1)) & 3) << 4);
        int cc = wc >> 1, sub = wc & 1;        // which 128-col chunk, which 64-half
        int rb = sub * 64 + f * 16 + l15;
        boff[f] = cc * 8192 + rb * 64 + (((l4 ^ (rb >> 1)) & 3) << 4);
    }

    // A staging: tid covers one 16B group per 8KB sub-chunk
    int ar, asl;
    {
        int r = tid >> 2, p = tid & 3;
        asl = (p ^ ((r >> 1) & 3)) & 3;
        ar = r;
    }

    f32x4 acc[4][4];
    #pragma unroll
    for (int i = 0; i < 4; i++)
        #pragma unroll
        for (int j = 0; j < 4; j++) acc[i][j] = (f32x4){0.f, 0.f, 0.f, 0.f};

    int NTc = 2 * NT;
    for (int t = 0; t < NT; t++) {
        int t2 = 2 * t;
        #pragma unroll
        for (int h = 0; h < 2; h++) {          // A halves -> 0, 8K
            const unsigned short* src = Abf + (size_t)(m0 + ar) * KP
                                      + (t2 + h) * 32 + asl * 8;
            gload16(src, sm + h * 8192 + tid * 16);
        }
        #pragma unroll
        for (int h = 0; h < 2; h++)            // B halves x col-chunks
            #pragma unroll
            for (int cc = 0; cc < 2; cc++) {
                size_t cb = (size_t)((2 * ct + cc) * NTc + t2 + h) * 8192;
                gload16(BhC + cb + tid * 16,
                        sm + 16384 + h * 16384 + cc * 8192 + tid * 16);
            }
        __syncthreads();
        #pragma unroll
        for (int h = 0; h < 2; h++) {
            const char* ab  = sm + h * 8192;
            const char* bb2 = sm + 16384 + h * 16384;
            s16x8 fah[4], fbh[4];
            #pragma unroll
            for (int f = 0; f < 4; f++) {
                fah[f] = *(const s16x8*)(ab + aoff[f]);
                fbh[f] = *(const s16x8*)(bb2 + boff[f]);
            }
            #pragma unroll
            for (int i = 0; i < 4; i++)
                #pragma unroll
                for (int j = 0; j < 4; j++)
                    acc[i][j] = __builtin_amdgcn_mfma_f32_16x16x32_bf16(fah[i], fbh[j], acc[i][j], 0, 0, 0);
        }
        __syncthreads();
    }

    if (MODE == 0) {
        float bc[4];
        #pragma unroll
        for (int f = 0; f < 4; f++) bc[f] = bias[n0 + wc * 64 + f * 16 + l15];
        float cs[4] = {0.f,0.f,0.f,0.f}, cq[4] = {0.f,0.f,0.f,0.f};
        #pragma unroll
        for (int i = 0; i < 4; i++) {
            int rowb = m0 + wr * 64 + i * 16 + l4 * 4;
            #pragma unroll
            for (int j2 = 0; j2 < 4; j2++) {
                unsigned short* hrow = Hbf + (size_t)(rowb + j2) * HD + n0 + wc * 64 + l15;
                #pragma unroll
                for (int f = 0; f < 4; f++) {
                    float v = acc[i][f][j2] + bc[f];
                    hrow[f * 16] = (unsigned short)cvtpk(v, v);
                    cs[f] += v; cq[f] += v * v;
                }
            }
        }
        #pragma unroll
        for (int m = 16; m < 64; m <<= 1)
            #pragma unroll
            for (int f = 0; f < 4; f++) {
                cs[f] += __shfl_xor(cs[f], m, 64);
                cq[f] += __shfl_xor(cq[f], m, 64);
            }
        if (l4 == 0) {
            #pragma unroll
            for (int f = 0; f < 4; f++) {
                int col = n0 + wc * 64 + f * 16 + l15;
                sp1[(size_t)col * 1024 + mb * 2 + wr] = cs[f];
                sp2[(size_t)col * 1024 + mb * 2 + wr] = cq[f];
            }
        }
    } else {
        float bc[4], w2[4][3];
        #pragma unroll
        for (int f = 0; f < 4; f++) {
            int col = n0 + wc * 64 + f * 16 + l15;
            bc[f] = bias[col];
            w2[f][0] = Wd2[col * 3 + 0]; w2[f][1] = Wd2[col * 3 + 1]; w2[f][2] = Wd2[col * 3 + 2];
        }
        float s0[16], s1[16], s2[16];
        #pragma unroll
        for (int i = 0; i < 16; i++) { s0[i] = 0.f; s1[i] = 0.f; s2[i] = 0.f; }
        #pragma unroll
        for (int i = 0; i < 4; i++)
            #pragma unroll
            for (int j2 = 0; j2 < 4; j2++) {
                int idx = i * 4 + j2;
                #pragma unroll
                for (int f = 0; f < 4; f++) {
                    float v = frelu(acc[i][f][j2] + bc[f]);
                    s0[idx] += v * w2[f][0];
                    s1[idx] += v * w2[f][1];
                    s2[idx] += v * w2[f][2];
                }
            }
        #pragma unroll
        for (int m = 1; m < 16; m <<= 1) {
            #pragma unroll
            for (int i = 0; i < 16; i++) {
                s0[i] += __shfl_xor(s0[i], m, 64);
                s1[i] += __shfl_xor(s1[i], m, 64);
                s2[i] += __shfl_xor(s2[i], m, 64);
            }
        }
        if (l15 == 0) {
            #pragma unroll
            for (int i = 0; i < 16; i++) {
                int row = m0 + wr * 64 + (i >> 2) * 16 + l4 * 4 + (i & 3);
                atomicAdd(&domacc[(size_t)row * 3 + 0], (double)s0[i]);
                atomicAdd(&domacc[(size_t)row * 3 + 1], (double)s1[i]);
                atomicAdd(&domacc[(size_t)row * 3 + 2], (double)s2[i]);
            }
        }
    }
}

// ---- BN final: reduce 1024 fp32 partials per column in fp64 ----------------
__global__ __launch_bounds__(256)
void bnfinal(const float* __restrict__ sp1, const float* __restrict__ sp2,
             const float* __restrict__ gamma, const float* __restrict__ beta,
             float* __restrict__ scale, float* __restrict__ shift)
{
    int c = blockIdx.x, t = threadIdx.x;
    const float* p1 = sp1 + (size_t)c * 1024;
    const float* p2 = sp2 + (size_t)c * 1024;
    double S = (double)p1[t] + (double)p1[t + 256] + (double)p1[t + 512] + (double)p1[t + 768];
    double Q = (double)p2[t] + (double)p2[t + 256] + (double)p2[t + 512] + (double)p2[t + 768];
    #pragma unroll
    for (int m = 1; m < 64; m <<= 1) { S += __shfl_xor(S, m, 64); Q += __shfl_xor(Q, m, 64); }
    __shared__ double sd1[4], sd2[4];
    int w = t >> 6;
    if ((t & 63) == 0) { sd1[w] = S; sd2[w] = Q; }
    __syncthreads();
    if (t == 0) {
        double Sa = sd1[0] + sd1[1] + sd1[2] + sd1[3];
        double Qa = sd2[0] + sd2[1] + sd2[2] + sd2[3];
        double mu  = Sa * (1.0 / 65536.0);
        double var = Qa * (1.0 / 65536.0) - mu * mu;
        double inv = 1.0 / sqrt(var + 1e-5);
        double sc  = inv * (double)gamma[c];
        double sh  = (double)beta[c] - mu * sc;
        scale[c] = (float)sc;
        shift[c] = (float)sh;
    }
}

// ---- dom_out finalize pass A: write outdom, flag borderline rows -----------
__global__ __launch_bounds__(256)
void domfinal_a(const double* __restrict__ domacc, const float* __restrict__ bd2,
                float* __restrict__ outdom, int* __restrict__ fixmeta, int* __restrict__ fixlist)
{
    int r = blockIdx.x * 256 + threadIdx.x;
    double v0 = domacc[(size_t)r * 3 + 0] + (double)bd2[0];
    double v1 = domacc[(size_t)r * 3 + 1] + (double)bd2[1];
    double v2 = domacc[(size_t)r * 3 + 2] + (double)bd2[2];
    outdom[(size_t)r * 3 + 0] = (float)v0;
    outdom[(size_t)r * 3 + 1] = (float)v1;
    outdom[(size_t)r * 3 + 2] = (float)v2;
    double mx01 = v0 > v1 ? v0 : v1, mn01 = v0 > v1 ? v1 : v0;
    double best = mx01 > v2 ? mx01 : v2;
    double m2   = mx01 > v2 ? (mn01 > v2 ? mn01 : v2) : mx01;
    if (best - m2 < 1.5e-2) {
        int p = atomicAdd(fixmeta, 1);
        fixlist[p] = r;
    }
}

// ---------------------------------------------------------------------------
// gfix1: 3-product MFMA recompute of h->feat for flagged rows (unchanged r24).
// ---------------------------------------------------------------------------
__global__ __launch_bounds__(256)
void gfix1(const int* __restrict__ fixmeta, const int* __restrict__ fixlist,
           const float* __restrict__ x,
           const char* __restrict__ BhC, const char* __restrict__ BlC,
           const float* __restrict__ b1, const float* __restrict__ scale,
           const float* __restrict__ shift,
           unsigned short* __restrict__ ffh, unsigned short* __restrict__ ffl)
{
    __shared__ __align__(16) char sm[32768];   // Ah | Al | Bh | Bl (8KB each)
    __shared__ int rowidx[128];
    int nfix = fixmeta[0]; if (nfix > FCAP) nfix = FCAP;
    int start = blockIdx.x * 128;
    if (start >= nfix) return;
    int nb = blockIdx.y;
    int n0 = nb << 7;

    int tid = threadIdx.x;
    int lane = tid & 63, wid = tid >> 6;
    int wr = wid >> 1, wc = wid & 1;
    int l15 = lane & 15, l4 = lane >> 4;

    if (tid < 128) {
        int i = start + tid;
        rowidx[tid] = fixlist[i < nfix ? i : nfix - 1];
    }
    __syncthreads();

    int aoff[4], boff[4];
    #pragma unroll
    for (int f = 0; f < 4; f++) {
        int ra = wr * 64 + f * 16 + l15;
        aoff[f] = ra * 64 + (((l4 ^ (ra >> 1)) & 3) << 4);
        int rb = wc * 64 + f * 16 + l15;
        boff[f] = rb * 64 + (((l4 ^ (rb >> 1)) & 3) << 4);
    }
    int ar[2], asl[2], arow[2];
    #pragma unroll
    for (int q = 0; q < 2; q++) {
        int idx = q * 256 + tid;
        int r = idx >> 2, p = idx & 3;
        asl[q] = (p ^ ((r >> 1) & 3)) & 3;
        ar[q] = r;
        arow[q] = rowidx[r];
    }

    f32x4 acc[4][4];
    #pragma unroll
    for (int i = 0; i < 4; i++)
        #pragma unroll
        for (int j = 0; j < 4; j++) acc[i][j] = (f32x4){0.f, 0.f, 0.f, 0.f};

    float av[2][8];
    auto loadA = [&](int t) {
        #pragma unroll
        for (int q = 0; q < 2; q++) {
            int kb = t * 32 + asl[q] * 8;
            const float* src = x + (size_t)arow[q] * KIN + kb;
            if (kb + 7 < KIN) {
                *(float4*)&av[q][0] = *(const float4*)src;
                *(float4*)&av[q][4] = *(const float4*)(src + 4);
            } else {
                #pragma unroll
                for (int e = 0; e < 8; e++) av[q][e] = (kb + e < KIN) ? src[e] : 0.f;
            }
        }
    };
    auto writeA = [&]() {
        #pragma unroll
        for (int q = 0; q < 2; q++) {
            int idx = q * 256 + tid;
            float* v = av[q];
            uint4 oh;
            oh.x = cvtpk(v[0], v[1]); oh.y = cvtpk(v[2], v[3]);
            oh.z = cvtpk(v[4], v[5]); oh.w = cvtpk(v[6], v[7]);
            float h0 = bf2f((unsigned short)(oh.x & 0xFFFF));
            float h1 = bf2f((unsigned short)(oh.x >> 16));
            float h2 = bf2f((unsigned short)(oh.y & 0xFFFF));
            float h3 = bf2f((unsigned short)(oh.y >> 16));
            float h4 = bf2f((unsigned short)(oh.z & 0xFFFF));
            float h5 = bf2f((unsigned short)(oh.z >> 16));
            float h6 = bf2f((unsigned short)(oh.w & 0xFFFF));
            float h7 = bf2f((unsigned short)(oh.w >> 16));
            uint4 ol;
            ol.x = cvtpk(v[0] - h0, v[1] - h1); ol.y = cvtpk(v[2] - h2, v[3] - h3);
            ol.z = cvtpk(v[4] - h4, v[5] - h5); ol.w = cvtpk(v[6] - h6, v[7] - h7);
            *(uint4*)(sm + idx * 16) = oh;
            *(uint4*)(sm + 8192 + idx * 16) = ol;
        }
    };

    loadA(0);
    const int NTc = 26;
    for (int t = 0; t < NTc; t++) {
        __syncthreads();
        size_t cb = (size_t)(nb * NTc + t) * 8192;
        #pragma unroll
        for (int q = 0; q < 2; q++) {
            int off = (q * 256 + tid) * 16;
            gload16(BhC + cb + off, sm + 16384 + off);
            gload16(BlC + cb + off, sm + 24576 + off);
        }
        writeA();
        if (t + 1 < NTc) loadA(t + 1);
        __syncthreads();
        s16x8 fah[4], fal[4], fbh[4], fbl[4];
        #pragma unroll
        for (int f = 0; f < 4; f++) {
            fah[f] = *(const s16x8*)(sm + aoff[f]);
            fal[f] = *(const s16x8*)(sm + 8192 + aoff[f]);
            fbh[f] = *(const s16x8*)(sm + 16384 + boff[f]);
            fbl[f] = *(const s16x8*)(sm + 24576 + boff[f]);
        }
        #pragma unroll
        for (int i = 0; i < 4; i++)
            #pragma unroll
            for (int j = 0; j < 4; j++) {
                acc[i][j] = __builtin_amdgcn_mfma_f32_16x16x32_bf16(fah[i], fbl[j], acc[i][j], 0, 0, 0);
                acc[i][j] = __builtin_amdgcn_mfma_f32_16x16x32_bf16(fal[i], fbh[j], acc[i][j], 0, 0, 0);
                acc[i][j] = __builtin_amdgcn_mfma_f32_16x16x32_bf16(fah[i], fbh[j], acc[i][j], 0, 0, 0);
            }
    }

    float bc[4], sc[4], sh[4];
    #pragma unroll
    for (int f = 0; f < 4; f++) {
        int col = n0 + wc * 64 + f * 16 + l15;
        bc[f] = b1[col]; sc[f] = scale[col]; sh[f] = shift[col];
    }
    #pragma unroll
    for (int i = 0; i < 4; i++) {
        #pragma unroll
        for (int j2 = 0; j2 < 4; j2++) {
            int pos = start + wr * 64 + i * 16 + l4 * 4 + j2;
            if (pos < nfix) {
                #pragma unroll
                for (int f = 0; f < 4; f++) {
                    int col = n0 + wc * 64 + f * 16 + l15;
                    float fl = frelu((acc[i][f][j2] + bc[f]) * sc[f] + sh[f]);
                    unsigned short hi = (unsigned short)cvtpk(fl, fl);
                    unsigned short lo = (unsigned short)cvtpk(fl - bf2f(hi), 0.f);
                    ffh[(size_t)pos * HD + col] = hi;
                    ffl[(size_t)pos * HD + col] = lo;
                }
            }
        }
    }
}

// ---------------------------------------------------------------------------
// gfix2: feat hi/lo planes @ Wd1 hi/lo (3-product) + Wd2 epilogue (unchanged).
// ---------------------------------------------------------------------------
__global__ __launch_bounds__(256)
void gfix2(const int* __restrict__ fixmeta,
           const unsigned short* __restrict__ ffh, const unsigned short* __restrict__ ffl,
           const char* __restrict__ BhC, const char* __restrict__ BlC,
           const float* __restrict__ bd1, const float* __restrict__ Wd2,
           double* __restrict__ domfix)
{
    __shared__ __align__(16) char sm[32768];
    int nfix = fixmeta[0]; if (nfix > FCAP) nfix = FCAP;
    int start = blockIdx.x * 128;
    if (start >= nfix) return;
    int nb = blockIdx.y;
    int n0 = nb << 7;

    int tid = threadIdx.x;
    int lane = tid & 63, wid = tid >> 6;
    int wr = wid >> 1, wc = wid & 1;
    int l15 = lane & 15, l4 = lane >> 4;

    int aoff[4], boff[4];
    #pragma unroll
    for (int f = 0; f < 4; f++) {
        int ra = wr * 64 + f * 16 + l15;
        aoff[f] = ra * 64 + (((l4 ^ (ra >> 1)) & 3) << 4);
        int rb = wc * 64 + f * 16 + l15;
        boff[f] = rb * 64 + (((l4 ^ (rb >> 1)) & 3) << 4);
    }
    int arow[2], asl[2];
    #pragma unroll
    for (int q = 0; q < 2; q++) {
        int idx = q * 256 + tid;
        int r = idx >> 2, p = idx & 3;
        asl[q] = (p ^ ((r >> 1) & 3)) & 3;
        int pos = start + r;
        arow[q] = pos < nfix ? pos : nfix - 1;
    }

    f32x4 acc[4][4];
    #pragma unroll
    for (int i = 0; i < 4; i++)
        #pragma unroll
        for (int j = 0; j < 4; j++) acc[i][j] = (f32x4){0.f, 0.f, 0.f, 0.f};

    const int NTc = 24;
    for (int t = 0; t < NTc; t++) {
        #pragma unroll
        for (int q = 0; q < 2; q++) {
            size_t ao = (size_t)arow[q] * HD + t * 32 + asl[q] * 8;
            gload16(ffh + ao, sm + (q * 256 + tid) * 16);
            gload16(ffl + ao, sm + 8192 + (q * 256 + tid) * 16);
        }
        size_t cb = (size_t)(nb * NTc + t) * 8192;
        #pragma unroll
        for (int q = 0; q < 2; q++) {
            int off = (q * 256 + tid) * 16;
            gload16(BhC + cb + off, sm + 16384 + off);
            gload16(BlC + cb + off, sm + 24576 + off);
        }
        __syncthreads();
        s16x8 fah[4], fal[4], fbh[4], fbl[4];
        #pragma unroll
        for (int f = 0; f < 4; f++) {
            fah[f] = *(const s16x8*)(sm + aoff[f]);
            fal[f] = *(const s16x8*)(sm + 8192 + aoff[f]);
            fbh[f] = *(const s16x8*)(sm + 16384 + boff[f]);
            fbl[f] = *(const s16x8*)(sm + 24576 + boff[f]);
        }
        #pragma unroll
        for (int i = 0; i < 4; i++)
            #pragma unroll
            for (int j = 0; j < 4; j++) {
                acc[i][j] = __builtin_amdgcn_mfma_f32_16x16x32_bf16(fah[i], fbl[j], acc[i][j], 0, 0, 0);
                acc[i][j] = __builtin_amdgcn_mfma_f32_16x16x32_bf16(fal[i], fbh[j], acc[i][j], 0, 0, 0);
                acc[i][j] = __builtin_amdgcn_mfma_f32_16x16x32_bf16(fah[i], fbh[j], acc[i][j], 0, 0, 0);
            }
        __syncthreads();
    }

    float bc[4], w2[4][3];
    #pragma unroll
    for (int f = 0; f < 4; f++) {
        int col = n0 + wc * 64 + f * 16 + l15;
        bc[f] = bd1[col];
        w2[f][0] = Wd2[col * 3 + 0]; w2[f][1] = Wd2[col * 3 + 1]; w2[f][2] = Wd2[col * 3 + 2];
    }
    float s0[16], s1[16], s2[16];
    #pragma unroll
    for (int i = 0; i < 16; i++) { s0[i] = 0.f; s1[i] = 0.f; s2[i] = 0.f; }
    #pragma unroll
    for (int i = 0; i < 4; i++)
        #pragma unroll
        for (int j2 = 0; j2 < 4; j2++) {
            int idx = i * 4 + j2;
            #pragma unroll
            for (int f = 0; f < 4; f++) {
                float v = frelu(acc[i][f][j2] + bc[f]);
                s0[idx] += v * w2[f][0];
                s1[idx] += v * w2[f][1];
                s2[idx] += v * w2[f][2];
            }
        }
    #pragma unroll
    for (int m = 1; m < 16; m <<= 1) {
        #pragma unroll
        for (int i = 0; i < 16; i++) {
            s0[i] += __shfl_xor(s0[i], m, 64);
            s1[i] += __shfl_xor(s1[i], m, 64);
            s2[i] += __shfl_xor(s2[i], m, 64);
        }
    }
    if (l15 == 0) {
        #pragma unroll
        for (int i = 0; i < 16; i++) {
            int pos = start + wr * 64 + (i >> 2) * 16 + l4 * 4 + (i & 3);
            if (pos < nfix) {
                atomicAdd(&domfix[(size_t)pos * 3 + 0], (double)s0[i]);
                atomicAdd(&domfix[(size_t)pos * 3 + 1], (double)s1[i]);
                atomicAdd(&domfix[(size_t)pos * 3 + 2], (double)s2[i]);
            }
        }
    }
}

// ---- fixfin: scatter recomputed dom back into outdom -----------------------
__global__ __launch_bounds__(256)
void fixfin(const int* __restrict__ fixmeta, const int* __restrict__ fixlist,
            const double* __restrict__ domfix, const float* __restrict__ bd2,
            float* __restrict__ outdom)
{
    int nfix = fixmeta[0]; if (nfix > FCAP) nfix = FCAP;
    int i = blockIdx.x * 256 + threadIdx.x;
    if (i < nfix) {
        int row = fixlist[i];
        outdom[(size_t)row * 3 + 0] = (float)(domfix[(size_t)i * 3 + 0] + (double)bd2[0]);
        outdom[(size_t)row * 3 + 1] = (float)(domfix[(size_t)i * 3 + 1] + (double)bd2[1]);
        outdom[(size_t)row * 3 + 2] = (float)(domfix[(size_t)i * 3 + 2] + (double)bd2[2]);
    }
}

// ---- pass B: argmax + bucket (block-aggregated atomics) --------------------
__global__ __launch_bounds__(256)
void domfinal_b(const float* __restrict__ outdom, int* __restrict__ cnt, int* __restrict__ lists)
{
    __shared__ int lcnt[3], base[3];
    int tid = threadIdx.x;
    if (tid < 3) lcnt[tid] = 0;
    __syncthreads();
    int r = blockIdx.x * 256 + tid;
    float v0 = outdom[(size_t)r * 3 + 0];
    float v1 = outdom[(size_t)r * 3 + 1];
    float v2 = outdom[(size_t)r * 3 + 2];
    int p = 0; float best = v0;
    if (v1 > best) { best = v1; p = 1; }
    if (v2 > best) { best = v2; p = 2; }
    int lpos = atomicAdd(&lcnt[p], 1);
    __syncthreads();
    if (tid < 3) base[tid] = atomicAdd(&cnt[tid], lcnt[tid]);
    __syncthreads();
    lists[(size_t)p * BATCH + base[p] + lpos] = r;
}

// ---- expert via MFMA: 128 gathered rows x 64(E) x K=768 per block ----------
__global__ __launch_bounds__(256)
void expert_mfma(const unsigned short* __restrict__ fbf,
                 const char* __restrict__ WaC,
                 const int* __restrict__ cnt, const int* __restrict__ lists,
                 const float* __restrict__ ba,
                 const float* __restrict__ Wb, const float* __restrict__ bb,
                 float* __restrict__ outs)
{
    __shared__ __align__(16) char sm[12288];   // A 8KB | B 4KB
    __shared__ float hid[128][66];
    __shared__ int rowidx[128];

    int d = blockIdx.y;
    int count = cnt[d];
    int start = blockIdx.x * 128;
    if (start >= count) return;
    int nrows = count - start; if (nrows > 128) nrows = 128;

    int tid = threadIdx.x;
    int lane = tid & 63, wid = tid >> 6;       // 4 waves stacked on M
    int l15 = lane & 15, l4 = lane >> 4;

    if (tid < 128) {
        int i = tid < nrows ? tid : nrows - 1;
        rowidx[tid] = lists[(size_t)d * BATCH + start + i];
    }
    __syncthreads();

    int asl[2], arow[2];
    #pragma unroll
    for (int q = 0; q < 2; q++) {
        int idx = q * 256 + tid;
        int r = idx >> 2, p = idx & 3;
        asl[q] = (p ^ ((r >> 1) & 3)) & 3;
        arow[q] = rowidx[r];
    }

    int aoff[2], boff[4];
    #pragma unroll
    for (int i2 = 0; i2 < 2; i2++) {
        int ra = wid * 32 + i2 * 16 + l15;
        aoff[i2] = ra * 64 + (((l4 ^ (ra >> 1)) & 3) << 4);
    }
    #pragma unroll
    for (int f = 0; f < 4; f++) {
        int rb = f * 16 + l15;
        boff[f] = rb * 64 + (((l4 ^ (rb >> 1)) & 3) << 4);
    }

    f32x4 acc[2][4];
    #pragma unroll
    for (int i = 0; i < 2; i++)
        #pragma unroll
        for (int j = 0; j < 4; j++) acc[i][j] = (f32x4){0.f, 0.f, 0.f, 0.f};

    for (int t = 0; t < 24; t++) {
        #pragma unroll
        for (int q = 0; q < 2; q++)
            gload16(fbf + (size_t)arow[q] * HD + t * 32 + asl[q] * 8,
                    sm + (q * 256 + tid) * 16);
        gload16(WaC + (size_t)(d * 24 + t) * 4096 + tid * 16, sm + 8192 + tid * 16);
        __syncthreads();
        s16x8 fa[2], fb[4];
        #pragma unroll
        for (int i2 = 0; i2 < 2; i2++) fa[i2] = *(const s16x8*)(sm + aoff[i2]);
        #pragma unroll
        for (int f = 0; f < 4; f++)    fb[f]  = *(const s16x8*)(sm + 8192 + boff[f]);
        #pragma unroll
        for (int i2 = 0; i2 < 2; i2++)
            #pragma unroll
            for (int f = 0; f < 4; f++)
                acc[i2][f] = __builtin_amdgcn_mfma_f32_16x16x32_bf16(fa[i2], fb[f], acc[i2][f], 0, 0, 0);
        __syncthreads();
    }

    #pragma unroll
    for (int i2 = 0; i2 < 2; i2++)
        #pragma unroll
        for (int f = 0; f < 4; f++) {
            int col = f * 16 + l15;
            float bav = ba[d * 64 + col];
            #pragma unroll
            for (int j = 0; j < 4; j++) {
                int row = wid * 32 + i2 * 16 + l4 * 4 + j;
                hid[row][col] = frelu(acc[i2][f][j] + bav);
            }
        }
    __syncthreads();

    for (int o = tid; o < 1280; o += 256) {
        int r2 = o / 10, c = o - r2 * 10;
        if (r2 < nrows) {
            float s = 0.f;
            #pragma unroll 16
            for (int l = 0; l < 64; l++) s += hid[r2][l] * Wb[((size_t)d * 64 + l) * 10 + c];
            outs[(size_t)rowidx[r2] * 10 + c] = s + bb[d * 10 + c];
        }
    }
}

// ---------------------------------------------------------------------------
extern "C" void kernel_launch(void* const* d_in, const int* in_sizes, int n_in,
                              void* d_out, int out_size, void* d_ws, size_t ws_size,
                              hipStream_t stream)
{
    const float* x     = (const float*)d_in[0];
    const float* W1    = (const float*)d_in[1];
    const float* b1    = (const float*)d_in[2];
    const float* gamma = (const float*)d_in[3];
    const float* beta  = (const float*)d_in[4];
    const float* Wd1   = (const float*)d_in[5];
    const float* bd1   = (const float*)d_in[6];
    const float* Wd2   = (const float*)d_in[7];
    const float* bd2   = (const float*)d_in[8];
    const float* Wa    = (const float*)d_in[9];
    const float* ba    = (const float*)d_in[10];
    const float* Wb    = (const float*)d_in[11];
    const float* bb    = (const float*)d_in[12];

    float* out    = (float*)d_out;
    float* outs   = out;
    float* outdom = out + (size_t)BATCH * 10;

    const int NT1 = 13, NT2 = 12;        // 64-k iterations (main gemms)
    const int NTC1 = 26, NTC2 = 24;      // 32-k chunks

    char* ws = (char*)d_ws;
    size_t off = 0;
    unsigned short* hbf = (unsigned short*)(ws + off); off += (size_t)BATCH * HD * 2;
    unsigned short* xbf = (unsigned short*)(ws + off); off += (size_t)BATCH * 832 * 2;
    unsigned short* fbf = xbf;           // alias: xbf dead after GEMM1
    unsigned short* ffh = hbf;           // hbf dead after featBN
    unsigned short* ffl = hbf + (size_t)FCAP * HD;
    char*  W1hC   = ws + off;            off += (size_t)6 * NTC1 * 8192;
    char*  W1loC  = ws + off;            off += (size_t)6 * NTC1 * 8192;
    char*  Wd1hC  = ws + off;            off += (size_t)6 * NTC2 * 8192;
    char*  Wd1loC = ws + off;            off += (size_t)6 * NTC2 * 8192;
    char*  WaC    = ws + off;            off += (size_t)3 * 24 * 4096;
    float* sp1    = (float*)(ws + off);  off += (size_t)HD * 1024 * 4;
    float* sp2    = (float*)(ws + off);  off += (size_t)HD * 1024 * 4;
    float* scale  = (float*)(ws + off);  off += HD * 4;
    float* shift  = (float*)(ws + off);  off += HD * 4;
    size_t zoff = off;
    double* domacc = (double*)(ws + off); off += (size_t)BATCH * 3 * 8;
    double* domfix = (double*)(ws + off); off += (size_t)FCAP * 3 * 8;
    int*    cnt    = (int*)(ws + off);    off += 64;
    int*    fixmeta= (int*)(ws + off);    off += 64;
    size_t zbytes = off - zoff;
    int*    lists  = (int*)(ws + off);    off += (size_t)3 * BATCH * 4;
    int*    fixlist= (int*)(ws + off);    off += (size_t)BATCH * 4;

    hipMemsetAsync(ws + zoff, 0, zbytes, stream);

    tileW<<<6 * NTC1, 256, 0, stream>>>(W1, W1hC, W1loC, KIN, HD, NTC1);
    tileW<<<6 * NTC2, 256, 0, stream>>>(Wd1, Wd1hC, Wd1loC, HD, HD, NTC2);
    tileWa<<<72, 256, 0, stream>>>(Wa, WaC);
    cvtX<<<BATCH * 104 / 256, 256, 0, stream>>>(x, xbf);

    gemm97<0><<<1536, 512, 0, stream>>>(xbf, W1hC, b1, hbf,
                                        nullptr, nullptr, sp1, sp2, 832, NT1);
    bnfinal<<<HD, 256, 0, stream>>>(sp1, sp2, gamma, beta, scale, shift);
    featBN<<<BATCH * 96 / 256, 256, 0, stream>>>(hbf, scale, shift, fbf);
    gemm97<1><<<1536, 512, 0, stream>>>(fbf, Wd1hC, bd1, nullptr,
                                        Wd2, domacc, nullptr, nullptr, HD, NT2);
    domfinal_a<<<BATCH / 256, 256, 0, stream>>>(domacc, bd2, outdom, fixmeta, fixlist);
    {
        dim3 fg(FCAP / 128, 6);
        gfix1<<<fg, 256, 0, stream>>>(fixmeta, fixlist, x, W1hC, W1loC,
                                      b1, scale, shift, ffh, ffl);
        gfix2<<<fg, 256, 0, stream>>>(fixmeta, ffh, ffl, Wd1hC, Wd1loC,
                                      bd1, Wd2, domfix);
        fixfin<<<FCAP / 256, 256, 0, stream>>>(fixmeta, fixlist, domfix, bd2, outdom);
    }
    domfinal_b<<<BATCH / 256, 256, 0, stream>>>(outdom, cnt, lists);
    dim3 eg(512, 3);
    expert_mfma<<<eg, 256, 0, stream>>>(fbf, WaC, cnt, lists, ba, Wb, bb, outs);
}

// Round 26
// 567.357 us; speedup vs baseline: 1.0387x; 1.0387x over previous
//
#include <hip/hip_runtime.h>
#include <math.h>

#define BATCH 65536
#define KIN   784
#define HD    768
#define FCAP  16384

typedef float f32x4 __attribute__((ext_vector_type(4)));
typedef short s16x8 __attribute__((ext_vector_type(8)));
typedef unsigned int __attribute__((address_space(3))) lds_u32;
typedef const unsigned int __attribute__((address_space(1))) glb_u32;

__device__ __forceinline__ float frelu(float x){ return x > 0.f ? x : 0.f; }

__device__ __forceinline__ unsigned int cvtpk(float a, float b){
    unsigned int r;
    asm("v_cvt_pk_bf16_f32 %0, %1, %2" : "=v"(r) : "v"(a), "v"(b));
    return r;
}
__device__ __forceinline__ unsigned short f2bf(float v){
    unsigned int u = __builtin_bit_cast(unsigned int, v);
    u += 0x7FFFu + ((u >> 16) & 1u);
    return (unsigned short)(u >> 16);
}
__device__ __forceinline__ float bf2f(unsigned short s){
    unsigned int u = ((unsigned int)s) << 16;
    return __builtin_bit_cast(float, u);
}
__device__ __forceinline__ void gload16(const void* g, void* l){
    __builtin_amdgcn_global_load_lds((glb_u32*)g, (lds_u32*)l, 16, 0, 0);
}

// ---------------------------------------------------------------------------
// x [B,784] fp32 -> xbf [B,832] bf16 (pad zeroed; 832 = 13*64 for BK=64).
// ---------------------------------------------------------------------------
__global__ __launch_bounds__(256)
void cvtX(const float* __restrict__ x, unsigned short* __restrict__ xbf)
{
    int idx = blockIdx.x * 256 + threadIdx.x;     // BATCH*104 total
    int row = idx / 104, c = (idx - row * 104) * 8;
    uint4 o = make_uint4(0, 0, 0, 0);
    if (c < KIN) {
        const float* p = x + (size_t)row * KIN + c;
        float4 a = *(const float4*)p;
        float4 b = *(const float4*)(p + 4);
        o.x = cvtpk(a.x, a.y); o.y = cvtpk(a.z, a.w);
        o.z = cvtpk(b.x, b.y); o.w = cvtpk(b.z, b.w);
    }
    *(uint4*)(xbf + (size_t)row * 832 + c) = o;
}

// ---------------------------------------------------------------------------
// feat = relu(hbf*scale + shift) -> fbf (bf16). 8 elems/thread.
// ---------------------------------------------------------------------------
__global__ __launch_bounds__(256)
void featBN(const unsigned short* __restrict__ hbf,
            const float* __restrict__ scale, const float* __restrict__ shift,
            unsigned short* __restrict__ fbf)
{
    int idx = blockIdx.x * 256 + threadIdx.x;     // BATCH*96 total
    int row = idx / 96, c = (idx - row * 96) * 8;
    s16x8 hv = *(const s16x8*)(hbf + (size_t)row * HD + c);
    float4 s0 = *(const float4*)(scale + c), s1 = *(const float4*)(scale + c + 4);
    float4 t0 = *(const float4*)(shift + c), t1 = *(const float4*)(shift + c + 4);
    float v[8];
    v[0] = frelu(bf2f((unsigned short)hv[0]) * s0.x + t0.x);
    v[1] = frelu(bf2f((unsigned short)hv[1]) * s0.y + t0.y);
    v[2] = frelu(bf2f((unsigned short)hv[2]) * s0.z + t0.z);
    v[3] = frelu(bf2f((unsigned short)hv[3]) * s0.w + t0.w);
    v[4] = frelu(bf2f((unsigned short)hv[4]) * s1.x + t1.x);
    v[5] = frelu(bf2f((unsigned short)hv[5]) * s1.y + t1.y);
    v[6] = frelu(bf2f((unsigned short)hv[6]) * s1.z + t1.z);
    v[7] = frelu(bf2f((unsigned short)hv[7]) * s1.w + t1.w);
    uint4 o;
    o.x = cvtpk(v[0], v[1]); o.y = cvtpk(v[2], v[3]);
    o.z = cvtpk(v[4], v[5]); o.w = cvtpk(v[6], v[7]);
    *(uint4*)(fbf + (size_t)row * HD + c) = o;
}

// ---------------------------------------------------------------------------
// Pre-tile W[K][N] fp32 -> bf16 hi AND lo 8KB swizzled chunks (128-col tiles).
// ---------------------------------------------------------------------------
__global__ __launch_bounds__(256)
void tileW(const float* __restrict__ W, char* __restrict__ Wh, char* __restrict__ Wl,
           int K, int N, int NT)
{
    int chunk = blockIdx.x;
    int nb = chunk / NT, t = chunk - nb * NT;
    int tid = threadIdx.x;
    #pragma unroll
    for (int q = 0; q < 2; q++) {
        int idx = q * 256 + tid;
        int r = idx >> 2, p = idx & 3;
        int s = (p ^ ((r >> 1) & 3)) & 3;
        int kb = t * 32 + s * 8;
        int n = nb * 128 + r;
        s16x8 hv, lv;
        #pragma unroll
        for (int e = 0; e < 8; e++) {
            int k = kb + e;
            float v = (k < K) ? W[(size_t)k * N + n] : 0.f;
            unsigned short h = f2bf(v);
            hv[e] = (short)h;
            lv[e] = (short)f2bf(v - bf2f(h));
        }
        *(s16x8*)(Wh + (size_t)chunk * 8192 + idx * 16) = hv;
        *(s16x8*)(Wl + (size_t)chunk * 8192 + idx * 16) = lv;
    }
}

// ---- Wa[d] 768x64 -> 24 chunks of 4KB per domain (64-row swizzled image) ---
__global__ __launch_bounds__(256)
void tileWa(const float* __restrict__ Wa, char* __restrict__ WaC)
{
    int chunk = blockIdx.x;            // d*24 + t
    int d = chunk / 24, t = chunk - d * 24;
    int idx = threadIdx.x;
    int r = idx >> 2, p = idx & 3;     // r = expert col (0..63)
    int s = (p ^ ((r >> 1) & 3)) & 3;
    int kb = t * 32 + s * 8;
    s16x8 hv;
    #pragma unroll
    for (int e = 0; e < 8; e++)
        hv[e] = (short)f2bf(Wa[((size_t)d * HD + kb + e) * 64 + r]);
    *(s16x8*)(WaC + (size_t)chunk * 4096 + idx * 16) = hv;
}

// ---------------------------------------------------------------------------
// m97-shaped bf16 GEMM, BK=64 (best-measured config: r23/r24; dual-M r21,
// dual-N r25, and all pipeline variants r18-r20 measured worse or neutral).
// MODE 0: A=xbf(KP=832); epilogue h(bf16) + fused BN column partials.
// MODE 1: A=fbf(KP=768); epilogue a=relu(acc+bd1); domacc += a @ Wd2.
// ---------------------------------------------------------------------------
template<int MODE>
__global__ __launch_bounds__(256, 3)
void gemm97(const unsigned short* __restrict__ Abf,
            const char* __restrict__ BhC,
            const float* __restrict__ bias,
            unsigned short* __restrict__ Hbf,
            const float* __restrict__ Wd2, double* __restrict__ domacc,
            float* __restrict__ sp1, float* __restrict__ sp2,
            int KP, int NT)
{
    __shared__ __align__(16) char sm[32768];   // A0 | A1 | B0 | B1 (8KB each)

    int bid = blockIdx.x;
    int wg = (bid & 7) * 384 + (bid >> 3);     // XCD-contiguous remap
    int mb = wg / 6, nb = wg - mb * 6;
    int m0 = mb << 7, n0 = nb << 7;

    int tid = threadIdx.x;
    int lane = tid & 63, wid = tid >> 6;
    int wr = wid >> 1, wc = wid & 1;
    int l15 = lane & 15, l4 = lane >> 4;

    int aoff[4], boff[4];
    #pragma unroll
    for (int f = 0; f < 4; f++) {
        int ra = wr * 64 + f * 16 + l15;
        aoff[f] = ra * 64 + (((l4 ^ (ra >> 1)) & 3) << 4);
        int rb = wc * 64 + f * 16 + l15;
        boff[f] = rb * 64 + (((l4 ^ (rb >> 1)) & 3) << 4);
    }

    int ar[2], asl[2];
    #pragma unroll
    for (int q = 0; q < 2; q++) {
        int idx = q * 256 + tid;
        int r = idx >> 2, p = idx & 3;
        asl[q] = (p ^ ((r >> 1) & 3)) & 3;
        ar[q] = r;
    }

    f32x4 acc[4][4];
    #pragma unroll
    for (int i = 0; i < 4; i++)
        #pragma unroll
        for (int j = 0; j < 4; j++) acc[i][j] = (f32x4){0.f, 0.f, 0.f, 0.f};

    int NTc = 2 * NT;
    for (int t = 0; t < NT; t++) {
        int t2 = 2 * t;
        #pragma unroll
        for (int h = 0; h < 2; h++) {
            #pragma unroll
            for (int q = 0; q < 2; q++) {
                const unsigned short* src = Abf + (size_t)(m0 + ar[q]) * KP
                                          + (t2 + h) * 32 + asl[q] * 8;
                gload16(src, sm + h * 8192 + (q * 256 + tid) * 16);
            }
        }
        #pragma unroll
        for (int h = 0; h < 2; h++) {
            size_t cb = (size_t)(nb * NTc + t2 + h) * 8192;
            #pragma unroll
            for (int q = 0; q < 2; q++) {
                int off = (q * 256 + tid) * 16;
                gload16(BhC + cb + off, sm + 16384 + h * 8192 + off);
            }
        }
        __syncthreads();
        #pragma unroll
        for (int h = 0; h < 2; h++) {
            const char* ab  = sm + h * 8192;
            const char* bb2 = sm + 16384 + h * 8192;
            s16x8 fah[4], fbh[4];
            #pragma unroll
            for (int f = 0; f < 4; f++) {
                fah[f] = *(const s16x8*)(ab + aoff[f]);
                fbh[f] = *(const s16x8*)(bb2 + boff[f]);
            }
            #pragma unroll
            for (int i = 0; i < 4; i++)
                #pragma unroll
                for (int j = 0; j < 4; j++)
                    acc[i][j] = __builtin_amdgcn_mfma_f32_16x16x32_bf16(fah[i], fbh[j], acc[i][j], 0, 0, 0);
        }
        __syncthreads();
    }

    if (MODE == 0) {
        float bc[4];
        #pragma unroll
        for (int f = 0; f < 4; f++) bc[f] = bias[n0 + wc * 64 + f * 16 + l15];
        float cs[4] = {0.f,0.f,0.f,0.f}, cq[4] = {0.f,0.f,0.f,0.f};
        #pragma unroll
        for (int i = 0; i < 4; i++) {
            int rowb = m0 + wr * 64 + i * 16 + l4 * 4;
            #pragma unroll
            for (int j2 = 0; j2 < 4; j2++) {
                unsigned short* hrow = Hbf + (size_t)(rowb + j2) * HD + n0 + wc * 64 + l15;
                #pragma unroll
                for (int f = 0; f < 4; f++) {
                    float v = acc[i][f][j2] + bc[f];
                    hrow[f * 16] = (unsigned short)cvtpk(v, v);
                    cs[f] += v; cq[f] += v * v;
                }
            }
        }
        #pragma unroll
        for (int m = 16; m < 64; m <<= 1)
            #pragma unroll
            for (int f = 0; f < 4; f++) {
                cs[f] += __shfl_xor(cs[f], m, 64);
                cq[f] += __shfl_xor(cq[f], m, 64);
            }
        if (l4 == 0) {
            #pragma unroll
            for (int f = 0; f < 4; f++) {
                int col = n0 + wc * 64 + f * 16 + l15;
                sp1[(size_t)col * 1024 + mb * 2 + wr] = cs[f];
                sp2[(size_t)col * 1024 + mb * 2 + wr] = cq[f];
            }
        }
    } else {
        float bc[4], w2[4][3];
        #pragma unroll
        for (int f = 0; f < 4; f++) {
            int col = n0 + wc * 64 + f * 16 + l15;
            bc[f] = bias[col];
            w2[f][0] = Wd2[col * 3 + 0]; w2[f][1] = Wd2[col * 3 + 1]; w2[f][2] = Wd2[col * 3 + 2];
        }
        float s0[16], s1[16], s2[16];
        #pragma unroll
        for (int i = 0; i < 16; i++) { s0[i] = 0.f; s1[i] = 0.f; s2[i] = 0.f; }
        #pragma unroll
        for (int i = 0; i < 4; i++)
            #pragma unroll
            for (int j2 = 0; j2 < 4; j2++) {
                int idx = i * 4 + j2;
                #pragma unroll
                for (int f = 0; f < 4; f++) {
                    float v = frelu(acc[i][f][j2] + bc[f]);
                    s0[idx] += v * w2[f][0];
                    s1[idx] += v * w2[f][1];
                    s2[idx] += v * w2[f][2];
                }
            }
        #pragma unroll
        for (int m = 1; m < 16; m <<= 1) {
            #pragma unroll
            for (int i = 0; i < 16; i++) {
                s0[i] += __shfl_xor(s0[i], m, 64);
                s1[i] += __shfl_xor(s1[i], m, 64);
                s2[i] += __shfl_xor(s2[i], m, 64);
            }
        }
        if (l15 == 0) {
            #pragma unroll
            for (int i = 0; i < 16; i++) {
                int row = m0 + wr * 64 + (i >> 2) * 16 + l4 * 4 + (i & 3);
                atomicAdd(&domacc[(size_t)row * 3 + 0], (double)s0[i]);
                atomicAdd(&domacc[(size_t)row * 3 + 1], (double)s1[i]);
                atomicAdd(&domacc[(size_t)row * 3 + 2], (double)s2[i]);
            }
        }
    }
}

// ---- BN final: reduce 1024 fp32 partials per column in fp64 ----------------
__global__ __launch_bounds__(256)
void bnfinal(const float* __restrict__ sp1, const float* __restrict__ sp2,
             const float* __restrict__ gamma, const float* __restrict__ beta,
             float* __restrict__ scale, float* __restrict__ shift)
{
    int c = blockIdx.x, t = threadIdx.x;
    const float* p1 = sp1 + (size_t)c * 1024;
    const float* p2 = sp2 + (size_t)c * 1024;
    double S = (double)p1[t] + (double)p1[t + 256] + (double)p1[t + 512] + (double)p1[t + 768];
    double Q = (double)p2[t] + (double)p2[t + 256] + (double)p2[t + 512] + (double)p2[t + 768];
    #pragma unroll
    for (int m = 1; m < 64; m <<= 1) { S += __shfl_xor(S, m, 64); Q += __shfl_xor(Q, m, 64); }
    __shared__ double sd1[4], sd2[4];
    int w = t >> 6;
    if ((t & 63) == 0) { sd1[w] = S; sd2[w] = Q; }
    __syncthreads();
    if (t == 0) {
        double Sa = sd1[0] + sd1[1] + sd1[2] + sd1[3];
        double Qa = sd2[0] + sd2[1] + sd2[2] + sd2[3];
        double mu  = Sa * (1.0 / 65536.0);
        double var = Qa * (1.0 / 65536.0) - mu * mu;
        double inv = 1.0 / sqrt(var + 1e-5);
        double sc  = inv * (double)gamma[c];
        double sh  = (double)beta[c] - mu * sc;
        scale[c] = (float)sc;
        shift[c] = (float)sh;
    }
}

// ---- dom_out finalize pass A: write outdom, flag borderline rows -----------
__global__ __launch_bounds__(256)
void domfinal_a(const double* __restrict__ domacc, const float* __restrict__ bd2,
                float* __restrict__ outdom, int* __restrict__ fixmeta, int* __restrict__ fixlist)
{
    int r = blockIdx.x * 256 + threadIdx.x;
    double v0 = domacc[(size_t)r * 3 + 0] + (double)bd2[0];
    double v1 = domacc[(size_t)r * 3 + 1] + (double)bd2[1];
    double v2 = domacc[(size_t)r * 3 + 2] + (double)bd2[2];
    outdom[(size_t)r * 3 + 0] = (float)v0;
    outdom[(size_t)r * 3 + 1] = (float)v1;
    outdom[(size_t)r * 3 + 2] = (float)v2;
    double mx01 = v0 > v1 ? v0 : v1, mn01 = v0 > v1 ? v1 : v0;
    double best = mx01 > v2 ? mx01 : v2;
    double m2   = mx01 > v2 ? (mn01 > v2 ? mn01 : v2) : mx01;
    if (best - m2 < 1.5e-2) {
        int p = atomicAdd(fixmeta, 1);
        fixlist[p] = r;
    }
}

// ---------------------------------------------------------------------------
// gfix1: 3-product MFMA recompute of h->feat for flagged rows (r2-r4 validated
// error class ~1e-5). A = gathered x rows, reg-staged with hi/lo split;
// B = W1 hi/lo chunks. Grid (FCAP/128, 6).
// ---------------------------------------------------------------------------
__global__ __launch_bounds__(256)
void gfix1(const int* __restrict__ fixmeta, const int* __restrict__ fixlist,
           const float* __restrict__ x,
           const char* __restrict__ BhC, const char* __restrict__ BlC,
           const float* __restrict__ b1, const float* __restrict__ scale,
           const float* __restrict__ shift,
           unsigned short* __restrict__ ffh, unsigned short* __restrict__ ffl)
{
    __shared__ __align__(16) char sm[32768];   // Ah | Al | Bh | Bl (8KB each)
    __shared__ int rowidx[128];
    int nfix = fixmeta[0]; if (nfix > FCAP) nfix = FCAP;
    int start = blockIdx.x * 128;
    if (start >= nfix) return;
    int nb = blockIdx.y;
    int n0 = nb << 7;

    int tid = threadIdx.x;
    int lane = tid & 63, wid = tid >> 6;
    int wr = wid >> 1, wc = wid & 1;
    int l15 = lane & 15, l4 = lane >> 4;

    if (tid < 128) {
        int i = start + tid;
        rowidx[tid] = fixlist[i < nfix ? i : nfix - 1];
    }
    __syncthreads();

    int aoff[4], boff[4];
    #pragma unroll
    for (int f = 0; f < 4; f++) {
        int ra = wr * 64 + f * 16 + l15;
        aoff[f] = ra * 64 + (((l4 ^ (ra >> 1)) & 3) << 4);
        int rb = wc * 64 + f * 16 + l15;
        boff[f] = rb * 64 + (((l4 ^ (rb >> 1)) & 3) << 4);
    }
    int ar[2], asl[2], arow[2];
    #pragma unroll
    for (int q = 0; q < 2; q++) {
        int idx = q * 256 + tid;
        int r = idx >> 2, p = idx & 3;
        asl[q] = (p ^ ((r >> 1) & 3)) & 3;
        ar[q] = r;
        arow[q] = rowidx[r];
    }

    f32x4 acc[4][4];
    #pragma unroll
    for (int i = 0; i < 4; i++)
        #pragma unroll
        for (int j = 0; j < 4; j++) acc[i][j] = (f32x4){0.f, 0.f, 0.f, 0.f};

    float av[2][8];
    auto loadA = [&](int t) {
        #pragma unroll
        for (int q = 0; q < 2; q++) {
            int kb = t * 32 + asl[q] * 8;
            const float* src = x + (size_t)arow[q] * KIN + kb;
            if (kb + 7 < KIN) {
                *(float4*)&av[q][0] = *(const float4*)src;
                *(float4*)&av[q][4] = *(const float4*)(src + 4);
            } else {
                #pragma unroll
                for (int e = 0; e < 8; e++) av[q][e] = (kb + e < KIN) ? src[e] : 0.f;
            }
        }
    };
    auto writeA = [&]() {
        #pragma unroll
        for (int q = 0; q < 2; q++) {
            int idx = q * 256 + tid;
            float* v = av[q];
            uint4 oh;
            oh.x = cvtpk(v[0], v[1]); oh.y = cvtpk(v[2], v[3]);
            oh.z = cvtpk(v[4], v[5]); oh.w = cvtpk(v[6], v[7]);
            float h0 = bf2f((unsigned short)(oh.x & 0xFFFF));
            float h1 = bf2f((unsigned short)(oh.x >> 16));
            float h2 = bf2f((unsigned short)(oh.y & 0xFFFF));
            float h3 = bf2f((unsigned short)(oh.y >> 16));
            float h4 = bf2f((unsigned short)(oh.z & 0xFFFF));
            float h5 = bf2f((unsigned short)(oh.z >> 16));
            float h6 = bf2f((unsigned short)(oh.w & 0xFFFF));
            float h7 = bf2f((unsigned short)(oh.w >> 16));
            uint4 ol;
            ol.x = cvtpk(v[0] - h0, v[1] - h1); ol.y = cvtpk(v[2] - h2, v[3] - h3);
            ol.z = cvtpk(v[4] - h4, v[5] - h5); ol.w = cvtpk(v[6] - h6, v[7] - h7);
            *(uint4*)(sm + idx * 16) = oh;
            *(uint4*)(sm + 8192 + idx * 16) = ol;
        }
    };

    loadA(0);
    const int NTc = 26;
    for (int t = 0; t < NTc; t++) {
        __syncthreads();
        size_t cb = (size_t)(nb * NTc + t) * 8192;
        #pragma unroll
        for (int q = 0; q < 2; q++) {
            int off = (q * 256 + tid) * 16;
            gload16(BhC + cb + off, sm + 16384 + off);
            gload16(BlC + cb + off, sm + 24576 + off);
        }
        writeA();
        if (t + 1 < NTc) loadA(t + 1);
        __syncthreads();
        s16x8 fah[4], fal[4], fbh[4], fbl[4];
        #pragma unroll
        for (int f = 0; f < 4; f++) {
            fah[f] = *(const s16x8*)(sm + aoff[f]);
            fal[f] = *(const s16x8*)(sm + 8192 + aoff[f]);
            fbh[f] = *(const s16x8*)(sm + 16384 + boff[f]);
            fbl[f] = *(const s16x8*)(sm + 24576 + boff[f]);
        }
        #pragma unroll
        for (int i = 0; i < 4; i++)
            #pragma unroll
            for (int j = 0; j < 4; j++) {
                acc[i][j] = __builtin_amdgcn_mfma_f32_16x16x32_bf16(fah[i], fbl[j], acc[i][j], 0, 0, 0);
                acc[i][j] = __builtin_amdgcn_mfma_f32_16x16x32_bf16(fal[i], fbh[j], acc[i][j], 0, 0, 0);
                acc[i][j] = __builtin_amdgcn_mfma_f32_16x16x32_bf16(fah[i], fbh[j], acc[i][j], 0, 0, 0);
            }
    }

    float bc[4], sc[4], sh[4];
    #pragma unroll
    for (int f = 0; f < 4; f++) {
        int col = n0 + wc * 64 + f * 16 + l15;
        bc[f] = b1[col]; sc[f] = scale[col]; sh[f] = shift[col];
    }
    #pragma unroll
    for (int i = 0; i < 4; i++) {
        #pragma unroll
        for (int j2 = 0; j2 < 4; j2++) {
            int pos = start + wr * 64 + i * 16 + l4 * 4 + j2;
            if (pos < nfix) {
                #pragma unroll
                for (int f = 0; f < 4; f++) {
                    int col = n0 + wc * 64 + f * 16 + l15;
                    float fl = frelu((acc[i][f][j2] + bc[f]) * sc[f] + sh[f]);
                    unsigned short hi = (unsigned short)cvtpk(fl, fl);
                    unsigned short lo = (unsigned short)cvtpk(fl - bf2f(hi), 0.f);
                    ffh[(size_t)pos * HD + col] = hi;
                    ffl[(size_t)pos * HD + col] = lo;
                }
            }
        }
    }
}

// ---------------------------------------------------------------------------
// gfix2: feat hi/lo planes @ Wd1 hi/lo (3-product) + Wd2 epilogue -> fp64
// atomics into domfix[pos][3]. Grid (FCAP/128, 6).
// ---------------------------------------------------------------------------
__global__ __launch_bounds__(256)
void gfix2(const int* __restrict__ fixmeta,
           const unsigned short* __restrict__ ffh, const unsigned short* __restrict__ ffl,
           const char* __restrict__ BhC, const char* __restrict__ BlC,
           const float* __restrict__ bd1, const float* __restrict__ Wd2,
           double* __restrict__ domfix)
{
    __shared__ __align__(16) char sm[32768];
    int nfix = fixmeta[0]; if (nfix > FCAP) nfix = FCAP;
    int start = blockIdx.x * 128;
    if (start >= nfix) return;
    int nb = blockIdx.y;
    int n0 = nb << 7;

    int tid = threadIdx.x;
    int lane = tid & 63, wid = tid >> 6;
    int wr = wid >> 1, wc = wid & 1;
    int l15 = lane & 15, l4 = lane >> 4;

    int aoff[4], boff[4];
    #pragma unroll
    for (int f = 0; f < 4; f++) {
        int ra = wr * 64 + f * 16 + l15;
        aoff[f] = ra * 64 + (((l4 ^ (ra >> 1)) & 3) << 4);
        int rb = wc * 64 + f * 16 + l15;
        boff[f] = rb * 64 + (((l4 ^ (rb >> 1)) & 3) << 4);
    }
    int arow[2], asl[2];
    #pragma unroll
    for (int q = 0; q < 2; q++) {
        int idx = q * 256 + tid;
        int r = idx >> 2, p = idx & 3;
        asl[q] = (p ^ ((r >> 1) & 3)) & 3;
        int pos = start + r;
        arow[q] = pos < nfix ? pos : nfix - 1;
    }

    f32x4 acc[4][4];
    #pragma unroll
    for (int i = 0; i < 4; i++)
        #pragma unroll
        for (int j = 0; j < 4; j++) acc[i][j] = (f32x4){0.f, 0.f, 0.f, 0.f};

    const int NTc = 24;
    for (int t = 0; t < NTc; t++) {
        #pragma unroll
        for (int q = 0; q < 2; q++) {
            size_t ao = (size_t)arow[q] * HD + t * 32 + asl[q] * 8;
            gload16(ffh + ao, sm + (q * 256 + tid) * 16);
            gload16(ffl + ao, sm + 8192 + (q * 256 + tid) * 16);
        }
        size_t cb = (size_t)(nb * NTc + t) * 8192;
        #pragma unroll
        for (int q = 0; q < 2; q++) {
            int off = (q * 256 + tid) * 16;
            gload16(BhC + cb + off, sm + 16384 + off);
            gload16(BlC + cb + off, sm + 24576 + off);
        }
        __syncthreads();
        s16x8 fah[4], fal[4], fbh[4], fbl[4];
        #pragma unroll
        for (int f = 0; f < 4; f++) {
            fah[f] = *(const s16x8*)(sm + aoff[f]);
            fal[f] = *(const s16x8*)(sm + 8192 + aoff[f]);
            fbh[f] = *(const s16x8*)(sm + 16384 + boff[f]);
            fbl[f] = *(const s16x8*)(sm + 24576 + boff[f]);
        }
        #pragma unroll
        for (int i = 0; i < 4; i++)
            #pragma unroll
            for (int j = 0; j < 4; j++) {
                acc[i][j] = __builtin_amdgcn_mfma_f32_16x16x32_bf16(fah[i], fbl[j], acc[i][j], 0, 0, 0);
                acc[i][j] = __builtin_amdgcn_mfma_f32_16x16x32_bf16(fal[i], fbh[j], acc[i][j], 0, 0, 0);
                acc[i][j] = __builtin_amdgcn_mfma_f32_16x16x32_bf16(fah[i], fbh[j], acc[i][j], 0, 0, 0);
            }
        __syncthreads();
    }

    float bc[4], w2[4][3];
    #pragma unroll
    for (int f = 0; f < 4; f++) {
        int col = n0 + wc * 64 + f * 16 + l15;
        bc[f] = bd1[col];
        w2[f][0] = Wd2[col * 3 + 0]; w2[f][1] = Wd2[col * 3 + 1]; w2[f][2] = Wd2[col * 3 + 2];
    }
    float s0[16], s1[16], s2[16];
    #pragma unroll
    for (int i = 0; i < 16; i++) { s0[i] = 0.f; s1[i] = 0.f; s2[i] = 0.f; }
    #pragma unroll
    for (int i = 0; i < 4; i++)
        #pragma unroll
        for (int j2 = 0; j2 < 4; j2++) {
            int idx = i * 4 + j2;
            #pragma unroll
            for (int f = 0; f < 4; f++) {
                float v = frelu(acc[i][f][j2] + bc[f]);
                s0[idx] += v * w2[f][0];
                s1[idx] += v * w2[f][1];
                s2[idx] += v * w2[f][2];
            }
        }
    #pragma unroll
    for (int m = 1; m < 16; m <<= 1) {
        #pragma unroll
        for (int i = 0; i < 16; i++) {
            s0[i] += __shfl_xor(s0[i], m, 64);
            s1[i] += __shfl_xor(s1[i], m, 64);
            s2[i] += __shfl_xor(s2[i], m, 64);
        }
    }
    if (l15 == 0) {
        #pragma unroll
        for (int i = 0; i < 16; i++) {
            int pos = start + wr * 64 + (i >> 2) * 16 + l4 * 4 + (i & 3);
            if (pos < nfix) {
                atomicAdd(&domfix[(size_t)pos * 3 + 0], (double)s0[i]);
                atomicAdd(&domfix[(size_t)pos * 3 + 1], (double)s1[i]);
                atomicAdd(&domfix[(size_t)pos * 3 + 2], (double)s2[i]);
            }
        }
    }
}

// ---- fixfin: scatter recomputed dom back into outdom -----------------------
__global__ __launch_bounds__(256)
void fixfin(const int* __restrict__ fixmeta, const int* __restrict__ fixlist,
            const double* __restrict__ domfix, const float* __restrict__ bd2,
            float* __restrict__ outdom)
{
    int nfix = fixmeta[0]; if (nfix > FCAP) nfix = FCAP;
    int i = blockIdx.x * 256 + threadIdx.x;
    if (i < nfix) {
        int row = fixlist[i];
        outdom[(size_t)row * 3 + 0] = (float)(domfix[(size_t)i * 3 + 0] + (double)bd2[0]);
        outdom[(size_t)row * 3 + 1] = (float)(domfix[(size_t)i * 3 + 1] + (double)bd2[1]);
        outdom[(size_t)row * 3 + 2] = (float)(domfix[(size_t)i * 3 + 2] + (double)bd2[2]);
    }
}

// ---- pass B: argmax + bucket (block-aggregated atomics) --------------------
__global__ __launch_bounds__(256)
void domfinal_b(const float* __restrict__ outdom, int* __restrict__ cnt, int* __restrict__ lists)
{
    __shared__ int lcnt[3], base[3];
    int tid = threadIdx.x;
    if (tid < 3) lcnt[tid] = 0;
    __syncthreads();
    int r = blockIdx.x * 256 + tid;
    float v0 = outdom[(size_t)r * 3 + 0];
    float v1 = outdom[(size_t)r * 3 + 1];
    float v2 = outdom[(size_t)r * 3 + 2];
    int p = 0; float best = v0;
    if (v1 > best) { best = v1; p = 1; }
    if (v2 > best) { best = v2; p = 2; }
    int lpos = atomicAdd(&lcnt[p], 1);
    __syncthreads();
    if (tid < 3) base[tid] = atomicAdd(&cnt[tid], lcnt[tid]);
    __syncthreads();
    lists[(size_t)p * BATCH + base[p] + lpos] = r;
}

// ---- expert via MFMA: 128 gathered rows x 64(E) x K=768 per block ----------
__global__ __launch_bounds__(256)
void expert_mfma(const unsigned short* __restrict__ fbf,
                 const char* __restrict__ WaC,
                 const int* __restrict__ cnt, const int* __restrict__ lists,
                 const float* __restrict__ ba,
                 const float* __restrict__ Wb, const float* __restrict__ bb,
                 float* __restrict__ outs)
{
    __shared__ __align__(16) char sm[12288];   // A 8KB | B 4KB
    __shared__ float hid[128][66];
    __shared__ int rowidx[128];

    int d = blockIdx.y;
    int count = cnt[d];
    int start = blockIdx.x * 128;
    if (start >= count) return;
    int nrows = count - start; if (nrows > 128) nrows = 128;

    int tid = threadIdx.x;
    int lane = tid & 63, wid = tid >> 6;       // 4 waves stacked on M
    int l15 = lane & 15, l4 = lane >> 4;

    if (tid < 128) {
        int i = tid < nrows ? tid : nrows - 1;
        rowidx[tid] = lists[(size_t)d * BATCH + start + i];
    }
    __syncthreads();

    int asl[2], arow[2];
    #pragma unroll
    for (int q = 0; q < 2; q++) {
        int idx = q * 256 + tid;
        int r = idx >> 2, p = idx & 3;
        asl[q] = (p ^ ((r >> 1) & 3)) & 3;
        arow[q] = rowidx[r];
    }

    int aoff[2], boff[4];
    #pragma unroll
    for (int i2 = 0; i2 < 2; i2++) {
        int ra = wid * 32 + i2 * 16 + l15;
        aoff[i2] = ra * 64 + (((l4 ^ (ra >> 1)) & 3) << 4);
    }
    #pragma unroll
    for (int f = 0; f < 4; f++) {
        int rb = f * 16 + l15;
        boff[f] = rb * 64 + (((l4 ^ (rb >> 1)) & 3) << 4);
    }

    f32x4 acc[2][4];
    #pragma unroll
    for (int i = 0; i < 2; i++)
        #pragma unroll
        for (int j = 0; j < 4; j++) acc[i][j] = (f32x4){0.f, 0.f, 0.f, 0.f};

    for (int t = 0; t < 24; t++) {
        #pragma unroll
        for (int q = 0; q < 2; q++)
            gload16(fbf + (size_t)arow[q] * HD + t * 32 + asl[q] * 8,
                    sm + (q * 256 + tid) * 16);
        gload16(WaC + (size_t)(d * 24 + t) * 4096 + tid * 16, sm + 8192 + tid * 16);
        __syncthreads();
        s16x8 fa[2], fb[4];
        #pragma unroll
        for (int i2 = 0; i2 < 2; i2++) fa[i2] = *(const s16x8*)(sm + aoff[i2]);
        #pragma unroll
        for (int f = 0; f < 4; f++)    fb[f]  = *(const s16x8*)(sm + 8192 + boff[f]);
        #pragma unroll
        for (int i2 = 0; i2 < 2; i2++)
            #pragma unroll
            for (int f = 0; f < 4; f++)
                acc[i2][f] = __builtin_amdgcn_mfma_f32_16x16x32_bf16(fa[i2], fb[f], acc[i2][f], 0, 0, 0);
        __syncthreads();
    }

    #pragma unroll
    for (int i2 = 0; i2 < 2; i2++)
        #pragma unroll
        for (int f = 0; f < 4; f++) {
            int col = f * 16 + l15;
            float bav = ba[d * 64 + col];
            #pragma unroll
            for (int j = 0; j < 4; j++) {
                int row = wid * 32 + i2 * 16 + l4 * 4 + j;
                hid[row][col] = frelu(acc[i2][f][j] + bav);
            }
        }
    __syncthreads();

    for (int o = tid; o < 1280; o += 256) {
        int r2 = o / 10, c = o - r2 * 10;
        if (r2 < nrows) {
            float s = 0.f;
            #pragma unroll 16
            for (int l = 0; l < 64; l++) s += hid[r2][l] * Wb[((size_t)d * 64 + l) * 10 + c];
            outs[(size_t)rowidx[r2] * 10 + c] = s + bb[d * 10 + c];
        }
    }
}

// ---------------------------------------------------------------------------
extern "C" void kernel_launch(void* const* d_in, const int* in_sizes, int n_in,
                              void* d_out, int out_size, void* d_ws, size_t ws_size,
                              hipStream_t stream)
{
    const float* x     = (const float*)d_in[0];
    const float* W1    = (const float*)d_in[1];
    const float* b1    = (const float*)d_in[2];
    const float* gamma = (const float*)d_in[3];
    const float* beta  = (const float*)d_in[4];
    const float* Wd1   = (const float*)d_in[5];
    const float* bd1   = (const float*)d_in[6];
    const float* Wd2   = (const float*)d_in[7];
    const float* bd2   = (const float*)d_in[8];
    const float* Wa    = (const float*)d_in[9];
    const float* ba    = (const float*)d_in[10];
    const float* Wb    = (const float*)d_in[11];
    const float* bb    = (const float*)d_in[12];

    float* out    = (float*)d_out;
    float* outs   = out;
    float* outdom = out + (size_t)BATCH * 10;

    const int NT1 = 13, NT2 = 12;        // 64-k iterations (main gemms)
    const int NTC1 = 26, NTC2 = 24;      // 32-k chunks

    char* ws = (char*)d_ws;
    size_t off = 0;
    unsigned short* hbf = (unsigned short*)(ws + off); off += (size_t)BATCH * HD * 2;
    unsigned short* xbf = (unsigned short*)(ws + off); off += (size_t)BATCH * 832 * 2;
    unsigned short* fbf = xbf;           // alias: xbf dead after GEMM1
    unsigned short* ffh = hbf;           // hbf dead after featBN
    unsigned short* ffl = hbf + (size_t)FCAP * HD;
    char*  W1hC   = ws + off;            off += (size_t)6 * NTC1 * 8192;
    char*  W1loC  = ws + off;            off += (size_t)6 * NTC1 * 8192;
    char*  Wd1hC  = ws + off;            off += (size_t)6 * NTC2 * 8192;
    char*  Wd1loC = ws + off;            off += (size_t)6 * NTC2 * 8192;
    char*  WaC    = ws + off;            off += (size_t)3 * 24 * 4096;
    float* sp1    = (float*)(ws + off);  off += (size_t)HD * 1024 * 4;
    float* sp2    = (float*)(ws + off);  off += (size_t)HD * 1024 * 4;
    float* scale  = (float*)(ws + off);  off += HD * 4;
    float* shift  = (float*)(ws + off);  off += HD * 4;
    size_t zoff = off;
    double* domacc = (double*)(ws + off); off += (size_t)BATCH * 3 * 8;
    double* domfix = (double*)(ws + off); off += (size_t)FCAP * 3 * 8;
    int*    cnt    = (int*)(ws + off);    off += 64;
    int*    fixmeta= (int*)(ws + off);    off += 64;
    size_t zbytes = off - zoff;
    int*    lists  = (int*)(ws + off);    off += (size_t)3 * BATCH * 4;
    int*    fixlist= (int*)(ws + off);    off += (size_t)BATCH * 4;

    hipMemsetAsync(ws + zoff, 0, zbytes, stream);

    tileW<<<6 * NTC1, 256, 0, stream>>>(W1, W1hC, W1loC, KIN, HD, NTC1);
    tileW<<<6 * NTC2, 256, 0, stream>>>(Wd1, Wd1hC, Wd1loC, HD, HD, NTC2);
    tileWa<<<72, 256, 0, stream>>>(Wa, WaC);
    cvtX<<<BATCH * 104 / 256, 256, 0, stream>>>(x, xbf);

    gemm97<0><<<3072, 256, 0, stream>>>(xbf, W1hC, b1, hbf,
                                        nullptr, nullptr, sp1, sp2, 832, NT1);
    bnfinal<<<HD, 256, 0, stream>>>(sp1, sp2, gamma, beta, scale, shift);
    featBN<<<BATCH * 96 / 256, 256, 0, stream>>>(hbf, scale, shift, fbf);
    gemm97<1><<<3072, 256, 0, stream>>>(fbf, Wd1hC, bd1, nullptr,
                                        Wd2, domacc, nullptr, nullptr, HD, NT2);
    domfinal_a<<<BATCH / 256, 256, 0, stream>>>(domacc, bd2, outdom, fixmeta, fixlist);
    {
        dim3 fg(FCAP / 128, 6);
        gfix1<<<fg, 256, 0, stream>>>(fixmeta, fixlist, x, W1hC, W1loC,
                                      b1, scale, shift, ffh, ffl);
        gfix2<<<fg, 256, 0, stream>>>(fixmeta, ffh, ffl, Wd1hC, Wd1loC,
                                      bd1, Wd2, domfix);
        fixfin<<<FCAP / 256, 256, 0, stream>>>(fixmeta, fixlist, domfix, bd2, outdom);
    }
    domfinal_b<<<BATCH / 256, 256, 0, stream>>>(outdom, cnt, lists);
    dim3 eg(512, 3);
    expert_mfma<<<eg, 256, 0, stream>>>(fbf, WaC, cnt, lists, ba, Wb, bb, outs);
}